// Round 1
// baseline (864.279 us; speedup 1.0000x reference)
//
#include <hip/hip_runtime.h>

// OrthogonalLayer1D: per-sample classical Gram-Schmidt.
// x: [M=8, S=65536, D=256] fp32.  One wave (64 lanes) per sample;
// each lane owns 4 contiguous elements (float4) of every vector.
// All 8 vectors live in registers (32 VGPRs), orthogonalized in place.

#define GS_M 8
#define GS_S 65536
#define GS_D 256

__device__ __forceinline__ float wave_reduce(float v) {
    // 64-lane butterfly sum; result broadcast to all lanes.
    #pragma unroll
    for (int off = 1; off < 64; off <<= 1)
        v += __shfl_xor(v, off, 64);
    return v;
}

__global__ __launch_bounds__(256) void gs_kernel(const float* __restrict__ x,
                                                 float* __restrict__ out) {
    const int gtid = blockIdx.x * blockDim.x + threadIdx.x;
    const int s    = gtid >> 6;   // one wave per sample
    const int lane = gtid & 63;

    const float4* __restrict__ xv = (const float4*)x;
    float4* __restrict__ ov = (float4*)out;

    // element offset (in float4 units): (m*S + s)*(D/4) + lane
    float4 v[GS_M];
    #pragma unroll
    for (int m = 0; m < GS_M; ++m)
        v[m] = xv[((size_t)m * GS_S + (size_t)s) * (GS_D / 4) + lane];

    #pragma unroll
    for (int i = 0; i < GS_M; ++i) {
        // classical GS: all coefficients against the ORIGINAL v[i],
        // then subtract all projections at once (matches reference).
        float coeff[GS_M];
        #pragma unroll
        for (int k = 0; k < i; ++k) {
            coeff[k] = v[i].x * v[k].x + v[i].y * v[k].y +
                       v[i].z * v[k].z + v[i].w * v[k].w;
        }
        // reduce all i partials (independent butterflies -> ILP)
        #pragma unroll
        for (int off = 1; off < 64; off <<= 1) {
            #pragma unroll
            for (int k = 0; k < i; ++k)
                coeff[k] += __shfl_xor(coeff[k], off, 64);
        }
        #pragma unroll
        for (int k = 0; k < i; ++k) {
            v[i].x -= coeff[k] * v[k].x;
            v[i].y -= coeff[k] * v[k].y;
            v[i].z -= coeff[k] * v[k].z;
            v[i].w -= coeff[k] * v[k].w;
        }
        // normalize
        float nrm2 = v[i].x * v[i].x + v[i].y * v[i].y +
                     v[i].z * v[i].z + v[i].w * v[i].w;
        nrm2 = wave_reduce(nrm2);
        const float r = rsqrtf(nrm2);
        v[i].x *= r; v[i].y *= r; v[i].z *= r; v[i].w *= r;

        ov[((size_t)i * GS_S + (size_t)s) * (GS_D / 4) + lane] = v[i];
    }
}

extern "C" void kernel_launch(void* const* d_in, const int* in_sizes, int n_in,
                              void* d_out, int out_size, void* d_ws, size_t ws_size,
                              hipStream_t stream) {
    const float* x = (const float*)d_in[0];
    float* out = (float*)d_out;
    // 256 threads = 4 waves/block, 1 sample per wave
    const int blocks = GS_S / 4;  // 16384
    gs_kernel<<<blocks, 256, 0, stream>>>(x, out);
}